// Round 8
// baseline (243.162 us; speedup 1.0000x reference)
//
#include <hip/hip_runtime.h>
#include <hip/hip_bf16.h>

typedef __bf16 bf16_t;
typedef __bf16 bf16x8 __attribute__((ext_vector_type(8)));
typedef float f32x4 __attribute__((ext_vector_type(4)));
typedef unsigned short u16x4 __attribute__((ext_vector_type(4)));

// Operand order: A = weight fragment (gate rows), B = x/h fragment (batch).
// C/D: col(lane&15) = batch, row(quad*4+r) = gate row.
#define MFMA16(a, b, c) __builtin_amdgcn_mfma_f32_16x16x32_bf16((a), (b), (c), 0, 0, 0)

#define BATCH 4096
#define SEQN 128
#define HN 256
#define NLABELS 100
#define TSTEPS 32
#define LEN_VN 1500
#define IPD_VN 256

// Workspace layout (bytes)
#define OFF_LENT   0u           // 1500*64*4 = 384000
#define OFF_IPDT   384000u      // 256*64*4  = 65536
#define OFF_WIH    449536u      // 768*256*2 = 393216
#define OFF_WHH    842752u      // 393216
#define OFF_GI     1235968u     // 4096*32*768*2 = 201326592

__device__ __forceinline__ float sigf(float x) {
    return __builtin_amdgcn_rcpf(1.f + __expf(-x));
}
__device__ __forceinline__ float tanh_fast(float x) {
    return 2.f * __builtin_amdgcn_rcpf(1.f + __expf(-2.f * x)) - 1.f;
}
__device__ __forceinline__ float b2f(unsigned short v) {
    union { unsigned u; float f; } c; c.u = ((unsigned)v) << 16; return c.f;
}
__device__ __forceinline__ f32x4 b2f4(u16x4 v) {
    f32x4 o;
    #pragma unroll
    for (int r = 0; r < 4; ++r) o[r] = b2f(v[r]);
    return o;
}
__device__ __forceinline__ unsigned short f2b(float f) {
    union { bf16_t h; unsigned short s; } c; c.h = (bf16_t)f; return c.s;
}

// LDS-only barrier: does not drain vmcnt; global loads/stores stay in flight.
__device__ __forceinline__ void barrier_lds() {
    asm volatile("s_waitcnt lgkmcnt(0)\n\ts_barrier" ::: "memory");
}

// ---------------------------------------------------------------------------
// K1: prep. blocks [0,439): fused embed+FC tables. [439,631): weight frags.
// frag order: wfrag[ct(48)][kt(8)][lane(64)][8], value =
//   W[ct*16 + (lane&15)][kt*32 + (lane>>4)*8 + j]
// ---------------------------------------------------------------------------
__global__ void prep_kernel(const float* __restrict__ len_emb,
                            const float* __restrict__ ipd_emb,
                            const float* __restrict__ fc_w,
                            const float* __restrict__ fc_b,
                            const float* __restrict__ w_ih,
                            const float* __restrict__ w_hh,
                            float* __restrict__ lenT, float* __restrict__ ipdT,
                            bf16_t* __restrict__ wfrag_ih,
                            bf16_t* __restrict__ wfrag_hh) {
    const int bid = blockIdx.x, tid = threadIdx.x;
    if (bid < 439) {
        const int row = bid * 4 + (tid >> 6);
        const int e = tid & 63;
        if (row < LEN_VN) {
            const float* emb = len_emb + row * 64;
            const float* wv = fc_w + e * 128;
            float s = fc_b[e];
            #pragma unroll 8
            for (int j = 0; j < 64; ++j) s += emb[j] * wv[j];
            lenT[row * 64 + e] = s;
        } else if (row < LEN_VN + IPD_VN) {
            const int v = row - LEN_VN;
            const float* emb = ipd_emb + v * 64;
            const float* wv = fc_w + e * 128 + 64;
            float s = 0.f;
            #pragma unroll 8
            for (int j = 0; j < 64; ++j) s += emb[j] * wv[j];
            ipdT[v * 64 + e] = s;
        }
    } else {
        const int flat = (bid - 439) * 256 + tid;   // 0..49151
        const int which = flat / 24576;
        const int rem = flat % 24576;
        const int c = rem >> 9;
        const int kt = (rem >> 6) & 7;
        const int lane = rem & 63;
        const int g = c * 16 + (lane & 15);
        const int k0 = kt * 32 + (lane >> 4) * 8;
        const float* src = (which == 0 ? w_ih : w_hh) + g * 256 + k0;
        bf16_t* dst = (which == 0 ? wfrag_ih : wfrag_hh) + ((c * 8 + kt) * 64 + lane) * 8;
        f32x4 s0 = *(const f32x4*)(src);
        f32x4 s1 = *(const f32x4*)(src + 4);
        bf16x8 o;
        #pragma unroll
        for (int j = 0; j < 4; ++j) { o[j] = (bf16_t)s0[j]; o[4 + j] = (bf16_t)s1[j]; }
        *(bf16x8*)dst = o;
    }
}

// ---------------------------------------------------------------------------
// K2: input-side GEMM + fused octet-coalesced gather + bias-init.
// 256 blocks x 512 threads (8 waves, 2/SIMD, 256-VGPR budget). Block owns 16
// batch rows. Wave w: gate tiles {2w,2w+1,16+2w,17+2w,32+2w} in regs,
// {33+2w} in LDS.
// NEW: 8-deep A-tile staging (2 groups x 4 steps) -> ONE barrier per 4 steps.
// No recurrence exists in this kernel, so waves may skew up to 4 steps:
// LDS reads / MFMA / epilogue VALU from different waves overlap instead of
// phase-locking, and barrier drains drop 32 -> 8.
// gi layout: [bt][ct(48)][t(32)][lane(64)][r(4)], biases pre-added
// (r,z: b_ih+b_hh; n: b_ih only).
// ---------------------------------------------------------------------------
__global__ void __launch_bounds__(512, 2)
gemm_gi(const int* __restrict__ len_x, const int* __restrict__ ipd_x,
        const float* __restrict__ lenT, const float* __restrict__ ipdT,
        const bf16_t* __restrict__ wfrag_ih,
        const float* __restrict__ b_ih, const float* __restrict__ b_hh,
        bf16_t* __restrict__ gi) {
    __shared__ bf16_t wlds[8 * 8 * 512];      // 64 KB: per-wave 6th tile
    __shared__ bf16_t a_lds[8][8 * 512];      // 64 KB: 2 groups x 4 t-slices

    const int tid = threadIdx.x;
    const int lane = tid & 63;
    const int w = tid >> 6;
    const int bt = blockIdx.x;
    const int quad = lane >> 4;

    const int cts[6] = {2*w, 2*w + 1, 16 + 2*w, 17 + 2*w, 32 + 2*w, 33 + 2*w};

    bf16x8 wr[5][8];
    #pragma unroll
    for (int cc = 0; cc < 5; ++cc)
        #pragma unroll
        for (int kt = 0; kt < 8; ++kt)
            wr[cc][kt] = *(const bf16x8*)(wfrag_ih + ((cts[cc] * 8 + kt) * 64 + lane) * 8);
    #pragma unroll
    for (int kt = 0; kt < 8; ++kt)
        *(bf16x8*)&wlds[(w * 8 + kt) * 512 + lane * 8] =
            *(const bf16x8*)(wfrag_ih + ((cts[5] * 8 + kt) * 64 + lane) * 8);

    // biases = acc init values: gate rows cts[cc]*16 + quad*4 + {0..3}
    f32x4 bias[6];
    #pragma unroll
    for (int cc = 0; cc < 6; ++cc) {
        f32x4 v = *(const f32x4*)(b_ih + cts[cc] * 16 + quad * 4);
        if (cc < 4) v += *(const f32x4*)(b_hh + cts[cc] * 16 + quad * 4);
        bias[cc] = v;
    }

    // octet gather mapping: 8 threads per (row, p) pair, 32 B contiguous each
    const int pair = tid >> 3;            // 0..63 = (p, row)
    const int sub = tid & 7;
    const int grow = pair & 15;
    const int p = pair >> 4;              // seq sub-position 0..3
    const int e0 = sub * 8;
    const int b_row = bt * 16 + grow;
    // LDS dst within a slice: kt = 2p + (sub>>2), quad' = sub&3
    const int goff = (2 * p + (sub >> 2)) * 512 + ((sub & 3) * 16 + grow) * 8;

    auto do_gather = [&](int t, int slot) {
        const int seq = t * 4 + p;
        const int v1 = len_x[b_row * SEQN + seq];
        const int v2 = ipd_x[b_row * SEQN + seq];
        const float* lp = lenT + v1 * 64 + e0;
        const float* ip = ipdT + v2 * 64 + e0;
        f32x4 a0 = *(const f32x4*)lp + *(const f32x4*)ip;
        f32x4 a1 = *(const f32x4*)(lp + 4) + *(const f32x4*)(ip + 4);
        bf16x8 o;
        #pragma unroll
        for (int j = 0; j < 4; ++j) { o[j] = (bf16_t)a0[j]; o[4 + j] = (bf16_t)a1[j]; }
        *(bf16x8*)&a_lds[slot][goff] = o;
    };

    // prologue: group 0 (t = 0..3) into slots 0..3
    #pragma unroll
    for (int q = 0; q < 4; ++q) do_gather(q, q);

    bf16_t* gib = gi + (size_t)bt * 48 * 32 * 256 + lane * 4;
    const bf16_t* wb = &wlds[w * 8 * 512 + lane * 8];

    for (int g = 0; g < 8; ++g) {
        barrier_lds();   // prev group's gathers (ds_writes) + reads of the
                         // parity about to be overwritten are all complete

        if (g < 7) {     // gather next group into the other parity
            const int base = 4 * ((g + 1) & 1);
            #pragma unroll
            for (int q = 0; q < 4; ++q) do_gather(4 * (g + 1) + q, base + q);
        }

        // 4 barrier-free GEMM steps; waves skew freely within the group
        #pragma unroll
        for (int q = 0; q < 4; ++q) {
            const int t = 4 * g + q;
            const bf16_t* ab = &a_lds[4 * (g & 1) + q][lane * 8];

            f32x4 acc[6];
            #pragma unroll
            for (int cc = 0; cc < 6; ++cc) acc[cc] = bias[cc];

            #pragma unroll
            for (int kt = 0; kt < 8; ++kt) {
                bf16x8 xf = *(const bf16x8*)(ab + kt * 512);
                bf16x8 w5 = *(const bf16x8*)(wb + kt * 512);
                acc[0] = MFMA16(wr[0][kt], xf, acc[0]);
                acc[1] = MFMA16(wr[1][kt], xf, acc[1]);
                acc[2] = MFMA16(wr[2][kt], xf, acc[2]);
                acc[3] = MFMA16(wr[3][kt], xf, acc[3]);
                acc[4] = MFMA16(wr[4][kt], xf, acc[4]);
                acc[5] = MFMA16(w5, xf, acc[5]);
            }

            #pragma unroll
            for (int cc = 0; cc < 6; ++cc) {
                u16x4 o;
                #pragma unroll
                for (int r = 0; r < 4; ++r) o[r] = f2b(acc[cc][r]);
                *(u16x4*)(gib + ((size_t)cts[cc] * 32 + t) * 256) = o;  // in flight
            }
        }
    }
}

// ---------------------------------------------------------------------------
// K3: recurrent GRU (UNCHANGED from round 7). 256 blocks x 1024 threads
// (16 waves, 4/SIMD). Wave w owns gate tiles {w, 16+w} in regs + {32+w}
// (n-gate) in LDS; lane owns 4 consecutive hidden cols -> b64 h-write.
// gi prefetched one step ahead; acc initialized from gi / b_hn.
// h double-buffered; one lgkm-only barrier per step.
// ---------------------------------------------------------------------------
__global__ void __launch_bounds__(1024, 4)
gru_kernel(const bf16_t* __restrict__ gi,
           const bf16_t* __restrict__ wfrag_hh,
           const float* __restrict__ b_hh,
           const float* __restrict__ out_w,
           const float* __restrict__ out_b,
           float* __restrict__ out) {
    __shared__ char smem[147456];
    bf16_t* wlds = (bf16_t*)smem;                 // 128 KB: per-wave n-tile
    bf16_t* h_lds = (bf16_t*)(smem + 131072);     // 2 x 8 KB double buffer
    float* h_fin = (float*)smem;                  // aliases wlds (post-loop)

    const int tid = threadIdx.x;
    const int lane = tid & 63;
    const int w = tid >> 6;
    const int bt = blockIdx.x;
    const int quad = lane >> 4;
    const int b = lane & 15;

    bf16x8 wr[2][8];
    #pragma unroll
    for (int cc = 0; cc < 2; ++cc) {
        const int ct = cc * 16 + w;
        #pragma unroll
        for (int kt = 0; kt < 8; ++kt)
            wr[cc][kt] = *(const bf16x8*)(wfrag_hh + ((ct * 8 + kt) * 64 + lane) * 8);
    }
    #pragma unroll
    for (int kt = 0; kt < 8; ++kt)
        *(bf16x8*)&wlds[(w * 8 + kt) * 512 + lane * 8] =
            *(const bf16x8*)(wfrag_hh + (((32 + w) * 8 + kt) * 64 + lane) * 8);

    const f32x4 bhn = *(const f32x4*)(b_hh + (32 + w) * 16 + quad * 4);

    for (int i = tid; i < 4096; i += 1024) h_lds[4096 + i] = (bf16_t)0.f;

    const int j0 = 16 * w + 4 * quad;
    const int woff = (j0 >> 5) * 512 + ((((j0 >> 3) & 3)) * 16 + b) * 8 + (j0 & 7);

    const bf16_t* gib = gi + (size_t)bt * 48 * 32 * 256 + lane * 4;
    const bf16_t* wb = &wlds[w * 8 * 512 + lane * 8];

    u16x4 gc0 = *(const u16x4*)(gib + ((size_t)(w) * 32) * 256);
    u16x4 gc1 = *(const u16x4*)(gib + ((size_t)(16 + w) * 32) * 256);
    u16x4 gc2 = *(const u16x4*)(gib + ((size_t)(32 + w) * 32) * 256);

    f32x4 hprev = {};

    for (int t = 0; t < TSTEPS; ++t) {
        barrier_lds();

        f32x4 acc0 = b2f4(gc0);
        f32x4 acc1 = b2f4(gc1);
        f32x4 acc2 = bhn;
        u16x4 g2cur = gc2;

        if (t + 1 < TSTEPS) {
            gc0 = *(const u16x4*)(gib + ((size_t)(w) * 32 + t + 1) * 256);
            gc1 = *(const u16x4*)(gib + ((size_t)(16 + w) * 32 + t + 1) * 256);
            gc2 = *(const u16x4*)(gib + ((size_t)(32 + w) * 32 + t + 1) * 256);
        }

        const bf16_t* hb = &h_lds[((t + 1) & 1) * 4096 + lane * 8];
        #pragma unroll
        for (int kt = 0; kt < 8; ++kt) {
            bf16x8 hf = *(const bf16x8*)(hb + kt * 512);
            bf16x8 w5 = *(const bf16x8*)(wb + kt * 512);
            acc0 = MFMA16(wr[0][kt], hf, acc0);
            acc1 = MFMA16(wr[1][kt], hf, acc1);
            acc2 = MFMA16(w5, hf, acc2);
        }

        f32x4 rg, zg;
        #pragma unroll
        for (int r = 0; r < 4; ++r) { rg[r] = sigf(acc0[r]); zg[r] = sigf(acc1[r]); }
        f32x4 u = b2f4(g2cur) + rg * acc2;
        f32x4 ng;
        #pragma unroll
        for (int r = 0; r < 4; ++r) ng[r] = tanh_fast(u[r]);
        f32x4 hn = ng + zg * (hprev - ng);
        hprev = hn;

        u16x4 o;
        #pragma unroll
        for (int r = 0; r < 4; ++r) o[r] = f2b(hn[r]);
        *(u16x4*)(&h_lds[(t & 1) * 4096 + woff]) = o;
    }

    __syncthreads();

    *(f32x4*)(h_fin + b * 260 + j0) = hprev;
    __syncthreads();

    for (int i = tid; i < 16 * NLABELS; i += 1024) {
        const int row = i / NLABELS;
        const int cl = i - row * NLABELS;
        const f32x4* wrow = (const f32x4*)(out_w + cl * 256);
        const f32x4* hr = (const f32x4*)(h_fin + row * 260);
        f32x4 acc = {0.f, 0.f, 0.f, 0.f};
        #pragma unroll 4
        for (int k = 0; k < 64; ++k) acc += hr[k] * wrow[k];
        out[(bt * 16 + row) * NLABELS + cl] =
            out_b[cl] + acc[0] + acc[1] + acc[2] + acc[3];
    }
}

// ---------------------------------------------------------------------------
extern "C" void kernel_launch(void* const* d_in, const int* in_sizes, int n_in,
                              void* d_out, int out_size, void* d_ws, size_t ws_size,
                              hipStream_t stream) {
    (void)in_sizes; (void)n_in; (void)out_size; (void)ws_size;
    const int*   len_x   = (const int*)d_in[0];
    const int*   ipd_x   = (const int*)d_in[1];
    const float* len_emb = (const float*)d_in[2];
    const float* ipd_emb = (const float*)d_in[3];
    const float* fc_w    = (const float*)d_in[4];
    const float* fc_b    = (const float*)d_in[5];
    const float* w_ih    = (const float*)d_in[6];
    const float* w_hh    = (const float*)d_in[7];
    const float* b_ih    = (const float*)d_in[8];
    const float* b_hh    = (const float*)d_in[9];
    const float* out_w   = (const float*)d_in[10];
    const float* out_b   = (const float*)d_in[11];

    char* ws = (char*)d_ws;
    float*  lenT = (float*)(ws + OFF_LENT);
    float*  ipdT = (float*)(ws + OFF_IPDT);
    bf16_t* wfi  = (bf16_t*)(ws + OFF_WIH);
    bf16_t* wfh  = (bf16_t*)(ws + OFF_WHH);
    bf16_t* gi   = (bf16_t*)(ws + OFF_GI);

    prep_kernel<<<631, 256, 0, stream>>>(len_emb, ipd_emb, fc_w, fc_b,
                                         w_ih, w_hh, lenT, ipdT, wfi, wfh);
    gemm_gi<<<256, 512, 0, stream>>>(len_x, ipd_x, lenT, ipdT, wfi,
                                     b_ih, b_hh, gi);
    gru_kernel<<<256, 1024, 0, stream>>>(gi, wfh, b_hh, out_w, out_b,
                                         (float*)d_out);
}

// Round 9
// 232.554 us; speedup vs baseline: 1.0456x; 1.0456x over previous
//
#include <hip/hip_runtime.h>
#include <hip/hip_bf16.h>

typedef __bf16 bf16_t;
typedef __bf16 bf16x8 __attribute__((ext_vector_type(8)));
typedef float f32x4 __attribute__((ext_vector_type(4)));
typedef unsigned short u16x4 __attribute__((ext_vector_type(4)));

// Operand order: A = weight fragment (gate rows), B = x/h fragment (batch).
// C/D: col(lane&15) = batch, row(quad*4+r) = gate row.
#define MFMA16(a, b, c) __builtin_amdgcn_mfma_f32_16x16x32_bf16((a), (b), (c), 0, 0, 0)

#define BATCH 4096
#define SEQN 128
#define HN 256
#define NLABELS 100
#define TSTEPS 32
#define LEN_VN 1500
#define IPD_VN 256

// Workspace layout (bytes)
#define OFF_LENT   0u           // 1500*64*4 = 384000
#define OFF_IPDT   384000u      // 256*64*4  = 65536
#define OFF_WIH    449536u      // 768*256*2 = 393216
#define OFF_WHH    842752u      // 393216
#define OFF_GI     1235968u     // 4096*32*768*2 = 201326592

__device__ __forceinline__ float sigf(float x) {
    return __builtin_amdgcn_rcpf(1.f + __expf(-x));
}
__device__ __forceinline__ float tanh_fast(float x) {
    return 2.f * __builtin_amdgcn_rcpf(1.f + __expf(-2.f * x)) - 1.f;
}
__device__ __forceinline__ float b2f(unsigned short v) {
    union { unsigned u; float f; } c; c.u = ((unsigned)v) << 16; return c.f;
}
__device__ __forceinline__ f32x4 b2f4(u16x4 v) {
    f32x4 o;
    #pragma unroll
    for (int r = 0; r < 4; ++r) o[r] = b2f(v[r]);
    return o;
}
__device__ __forceinline__ unsigned short f2b(float f) {
    union { bf16_t h; unsigned short s; } c; c.h = (bf16_t)f; return c.s;
}

// LDS-only barrier: does not drain vmcnt; global loads/stores stay in flight.
__device__ __forceinline__ void barrier_lds() {
    asm volatile("s_waitcnt lgkmcnt(0)\n\ts_barrier" ::: "memory");
}
// Per-wave drain of all outstanding global ops (phase boundary).
__device__ __forceinline__ void wait_vm0() {
    asm volatile("s_waitcnt vmcnt(0)" ::: "memory");
}

// ---------------------------------------------------------------------------
// K1: prep. blocks [0,439): fused embed+FC tables. [439,631): weight frags.
// frag order: wfrag[ct(48)][kt(8)][lane(64)][8], value =
//   W[ct*16 + (lane&15)][kt*32 + (lane>>4)*8 + j]
// ---------------------------------------------------------------------------
__global__ void prep_kernel(const float* __restrict__ len_emb,
                            const float* __restrict__ ipd_emb,
                            const float* __restrict__ fc_w,
                            const float* __restrict__ fc_b,
                            const float* __restrict__ w_ih,
                            const float* __restrict__ w_hh,
                            float* __restrict__ lenT, float* __restrict__ ipdT,
                            bf16_t* __restrict__ wfrag_ih,
                            bf16_t* __restrict__ wfrag_hh) {
    const int bid = blockIdx.x, tid = threadIdx.x;
    if (bid < 439) {
        const int row = bid * 4 + (tid >> 6);
        const int e = tid & 63;
        if (row < LEN_VN) {
            const float* emb = len_emb + row * 64;
            const float* wv = fc_w + e * 128;
            float s = fc_b[e];
            #pragma unroll 8
            for (int j = 0; j < 64; ++j) s += emb[j] * wv[j];
            lenT[row * 64 + e] = s;
        } else if (row < LEN_VN + IPD_VN) {
            const int v = row - LEN_VN;
            const float* emb = ipd_emb + v * 64;
            const float* wv = fc_w + e * 128 + 64;
            float s = 0.f;
            #pragma unroll 8
            for (int j = 0; j < 64; ++j) s += emb[j] * wv[j];
            ipdT[v * 64 + e] = s;
        }
    } else {
        const int flat = (bid - 439) * 256 + tid;   // 0..49151
        const int which = flat / 24576;
        const int rem = flat % 24576;
        const int c = rem >> 9;
        const int kt = (rem >> 6) & 7;
        const int lane = rem & 63;
        const int g = c * 16 + (lane & 15);
        const int k0 = kt * 32 + (lane >> 4) * 8;
        const float* src = (which == 0 ? w_ih : w_hh) + g * 256 + k0;
        bf16_t* dst = (which == 0 ? wfrag_ih : wfrag_hh) + ((c * 8 + kt) * 64 + lane) * 8;
        f32x4 s0 = *(const f32x4*)(src);
        f32x4 s1 = *(const f32x4*)(src + 4);
        bf16x8 o;
        #pragma unroll
        for (int j = 0; j < 4; ++j) { o[j] = (bf16_t)s0[j]; o[4 + j] = (bf16_t)s1[j]; }
        *(bf16x8*)dst = o;
    }
}

// ---------------------------------------------------------------------------
// K2: FUSED input-GEMM + GRU. 256 blocks x 1024 threads (16 waves, 4/SIMD,
// 128-VGPR cap). Block bt owns batch rows [bt*16, bt*16+16) end-to-end.
//
// Phase 1 (input GEMM): wave w owns gate tiles {w, 16+w} in regs + {32+w}
//   (n-gate) in wlds. x-tile octet-gathered (tid<512) into a 2x8KB double
//   buffer; one lgkm-only barrier per step; acc init from folded biases;
//   gi written to global (stays in flight across barriers).
// Phase 2 (GRU): per-wave s_waitcnt vmcnt(0) — each wave reads back ONLY
//   gi it wrote itself (same lanes, same addresses), so no cross-wave
//   ordering is needed. wlds reloaded with w_hh n-tiles; the x staging
//   region becomes the h double buffer; r7-K3 loop unchanged.
//
// No inter-kernel dispatch boundary between GEMM and GRU: saves the
// drain/launch gap and keeps gi XCD-local for the readback.
// gi layout: [bt][ct(48)][t(32)][lane(64)][r(4)]; r,z biases = b_ih+b_hh,
// n bias = b_ih (b_hh n-part folded into phase-2 acc init).
// ---------------------------------------------------------------------------
__global__ void __launch_bounds__(1024, 4)
fused_kernel(const int* __restrict__ len_x, const int* __restrict__ ipd_x,
             const float* __restrict__ lenT, const float* __restrict__ ipdT,
             const bf16_t* __restrict__ wfrag_ih,
             const bf16_t* __restrict__ wfrag_hh,
             const float* __restrict__ b_ih, const float* __restrict__ b_hh,
             bf16_t* gi,
             const float* __restrict__ out_w,
             const float* __restrict__ out_b,
             float* __restrict__ out) {
    __shared__ char smem[147456];
    bf16_t* wlds = (bf16_t*)smem;               // 128 KB: per-wave n-tile
    bf16_t* dbuf = (bf16_t*)(smem + 131072);    // 16 KB: x-stage / h double buf
    float* h_fin = (float*)smem;                // aliases wlds (post-loop)

    const int tid = threadIdx.x;
    const int lane = tid & 63;
    const int w = tid >> 6;          // wave 0..15
    const int bt = blockIdx.x;
    const int quad = lane >> 4;
    const int b = lane & 15;

    bf16_t* gib = gi + (size_t)bt * 48 * 32 * 256 + lane * 4;
    const bf16_t* wb = &wlds[w * 8 * 512 + lane * 8];

    // ===================== PHASE 1: input-side GEMM ========================
    {
        // weights: tiles {w, 16+w} in regs, {32+w} (n-gate) to wlds
        bf16x8 wri[2][8];
        #pragma unroll
        for (int cc = 0; cc < 2; ++cc) {
            const int ct = cc * 16 + w;
            #pragma unroll
            for (int kt = 0; kt < 8; ++kt)
                wri[cc][kt] = *(const bf16x8*)(wfrag_ih + ((ct * 8 + kt) * 64 + lane) * 8);
        }
        #pragma unroll
        for (int kt = 0; kt < 8; ++kt)
            *(bf16x8*)&wlds[(w * 8 + kt) * 512 + lane * 8] =
                *(const bf16x8*)(wfrag_ih + (((32 + w) * 8 + kt) * 64 + lane) * 8);

        // acc-init biases: rows ct*16 + quad*4 + {0..3}
        f32x4 bias0 = *(const f32x4*)(b_ih + w * 16 + quad * 4)
                    + *(const f32x4*)(b_hh + w * 16 + quad * 4);
        f32x4 bias1 = *(const f32x4*)(b_ih + 256 + w * 16 + quad * 4)
                    + *(const f32x4*)(b_hh + 256 + w * 16 + quad * 4);
        f32x4 bias2 = *(const f32x4*)(b_ih + 512 + w * 16 + quad * 4);

        // octet gather (tid < 512): 8 threads per (row, p), 32 B contiguous
        const int sub = tid & 511;
        const int pr = sub >> 3;             // 0..63 = (p, row)
        const int sub8 = sub & 7;
        const int grow = pr & 15;
        const int p = pr >> 4;               // seq sub-position 0..3
        const int e0 = sub8 * 8;
        const int b_row = bt * 16 + grow;
        const int goff = (2 * p + (sub8 >> 2)) * 512 + ((sub8 & 3) * 16 + grow) * 8;

        auto do_gather = [&](int t) {
            const int seq = t * 4 + p;
            const int v1 = len_x[b_row * SEQN + seq];
            const int v2 = ipd_x[b_row * SEQN + seq];
            const float* lp = lenT + v1 * 64 + e0;
            const float* ip = ipdT + v2 * 64 + e0;
            f32x4 a0 = *(const f32x4*)lp + *(const f32x4*)ip;
            f32x4 a1 = *(const f32x4*)(lp + 4) + *(const f32x4*)(ip + 4);
            bf16x8 o;
            #pragma unroll
            for (int j = 0; j < 4; ++j) { o[j] = (bf16_t)a0[j]; o[4 + j] = (bf16_t)a1[j]; }
            *(bf16x8*)&dbuf[(t & 1) * 4096 + goff] = o;
        };

        if (tid < 512) do_gather(0);

        for (int t = 0; t < TSTEPS; ++t) {
            barrier_lds();               // stage[t&1] writes + prior reads ordered
            if (t + 1 < TSTEPS && tid < 512) do_gather(t + 1);

            f32x4 acc0 = bias0, acc1 = bias1, acc2 = bias2;
            const bf16_t* ab = &dbuf[(t & 1) * 4096 + lane * 8];
            #pragma unroll
            for (int kt = 0; kt < 8; ++kt) {
                bf16x8 xf = *(const bf16x8*)(ab + kt * 512);
                bf16x8 w5 = *(const bf16x8*)(wb + kt * 512);
                acc0 = MFMA16(wri[0][kt], xf, acc0);
                acc1 = MFMA16(wri[1][kt], xf, acc1);
                acc2 = MFMA16(w5, xf, acc2);
            }

            u16x4 o0, o1, o2;
            #pragma unroll
            for (int r = 0; r < 4; ++r) {
                o0[r] = f2b(acc0[r]); o1[r] = f2b(acc1[r]); o2[r] = f2b(acc2[r]);
            }
            // stores stay in flight across the lgkm barriers
            *(u16x4*)(gib + ((size_t)(w) * 32 + t) * 256) = o0;
            *(u16x4*)(gib + ((size_t)(16 + w) * 32 + t) * 256) = o1;
            *(u16x4*)(gib + ((size_t)(32 + w) * 32 + t) * 256) = o2;
        }
    }

    // ===================== PHASE boundary ==================================
    barrier_lds();     // all phase-1 wlds/stage reads complete in every wave
    wait_vm0();        // own gi stores landed (we read back only our own)

    // ===================== PHASE 2: recurrent GRU ==========================
    bf16_t* h_lds = dbuf;    // 2 x 8 KB double buffer (reuses x stage)

    bf16x8 wr[2][8];
    #pragma unroll
    for (int cc = 0; cc < 2; ++cc) {
        const int ct = cc * 16 + w;
        #pragma unroll
        for (int kt = 0; kt < 8; ++kt)
            wr[cc][kt] = *(const bf16x8*)(wfrag_hh + ((ct * 8 + kt) * 64 + lane) * 8);
    }
    #pragma unroll
    for (int kt = 0; kt < 8; ++kt)
        *(bf16x8*)&wlds[(w * 8 + kt) * 512 + lane * 8] =
            *(const bf16x8*)(wfrag_hh + (((32 + w) * 8 + kt) * 64 + lane) * 8);

    const f32x4 bhn = *(const f32x4*)(b_hh + (32 + w) * 16 + quad * 4);

    // zero the t=0 read buffer (buf index 1)
    for (int i = tid; i < 4096; i += 1024) h_lds[4096 + i] = (bf16_t)0.f;

    const int j0 = 16 * w + 4 * quad;
    const int woff = (j0 >> 5) * 512 + ((((j0 >> 3) & 3)) * 16 + b) * 8 + (j0 & 7);

    u16x4 gc0 = *(const u16x4*)(gib + ((size_t)(w) * 32) * 256);
    u16x4 gc1 = *(const u16x4*)(gib + ((size_t)(16 + w) * 32) * 256);
    u16x4 gc2 = *(const u16x4*)(gib + ((size_t)(32 + w) * 32) * 256);

    f32x4 hprev = {};

    for (int t = 0; t < TSTEPS; ++t) {
        barrier_lds();   // setup (t=0) / prev step's h writes visible

        f32x4 acc0 = b2f4(gc0);
        f32x4 acc1 = b2f4(gc1);
        f32x4 acc2 = bhn;
        u16x4 g2cur = gc2;

        if (t + 1 < TSTEPS) {
            gc0 = *(const u16x4*)(gib + ((size_t)(w) * 32 + t + 1) * 256);
            gc1 = *(const u16x4*)(gib + ((size_t)(16 + w) * 32 + t + 1) * 256);
            gc2 = *(const u16x4*)(gib + ((size_t)(32 + w) * 32 + t + 1) * 256);
        }

        const bf16_t* hb = &h_lds[((t + 1) & 1) * 4096 + lane * 8];
        #pragma unroll
        for (int kt = 0; kt < 8; ++kt) {
            bf16x8 hf = *(const bf16x8*)(hb + kt * 512);
            bf16x8 w5 = *(const bf16x8*)(wb + kt * 512);
            acc0 = MFMA16(wr[0][kt], hf, acc0);
            acc1 = MFMA16(wr[1][kt], hf, acc1);
            acc2 = MFMA16(w5, hf, acc2);
        }

        f32x4 rg, zg;
        #pragma unroll
        for (int r = 0; r < 4; ++r) { rg[r] = sigf(acc0[r]); zg[r] = sigf(acc1[r]); }
        f32x4 u = b2f4(g2cur) + rg * acc2;
        f32x4 ng;
        #pragma unroll
        for (int r = 0; r < 4; ++r) ng[r] = tanh_fast(u[r]);
        f32x4 hn = ng + zg * (hprev - ng);
        hprev = hn;

        u16x4 o;
        #pragma unroll
        for (int r = 0; r < 4; ++r) o[r] = f2b(hn[r]);
        *(u16x4*)(&h_lds[(t & 1) * 4096 + woff]) = o;
    }

    __syncthreads();     // all wlds reads done -> safe to alias h_fin

    *(f32x4*)(h_fin + b * 260 + j0) = hprev;
    __syncthreads();

    for (int i = tid; i < 16 * NLABELS; i += 1024) {
        const int row = i / NLABELS;
        const int cl = i - row * NLABELS;
        const f32x4* wrow = (const f32x4*)(out_w + cl * 256);
        const f32x4* hr = (const f32x4*)(h_fin + row * 260);
        f32x4 acc = {0.f, 0.f, 0.f, 0.f};
        #pragma unroll 4
        for (int k = 0; k < 64; ++k) acc += hr[k] * wrow[k];
        out[(bt * 16 + row) * NLABELS + cl] =
            out_b[cl] + acc[0] + acc[1] + acc[2] + acc[3];
    }
}

// ---------------------------------------------------------------------------
extern "C" void kernel_launch(void* const* d_in, const int* in_sizes, int n_in,
                              void* d_out, int out_size, void* d_ws, size_t ws_size,
                              hipStream_t stream) {
    (void)in_sizes; (void)n_in; (void)out_size; (void)ws_size;
    const int*   len_x   = (const int*)d_in[0];
    const int*   ipd_x   = (const int*)d_in[1];
    const float* len_emb = (const float*)d_in[2];
    const float* ipd_emb = (const float*)d_in[3];
    const float* fc_w    = (const float*)d_in[4];
    const float* fc_b    = (const float*)d_in[5];
    const float* w_ih    = (const float*)d_in[6];
    const float* w_hh    = (const float*)d_in[7];
    const float* b_ih    = (const float*)d_in[8];
    const float* b_hh    = (const float*)d_in[9];
    const float* out_w   = (const float*)d_in[10];
    const float* out_b   = (const float*)d_in[11];

    char* ws = (char*)d_ws;
    float*  lenT = (float*)(ws + OFF_LENT);
    float*  ipdT = (float*)(ws + OFF_IPDT);
    bf16_t* wfi  = (bf16_t*)(ws + OFF_WIH);
    bf16_t* wfh  = (bf16_t*)(ws + OFF_WHH);
    bf16_t* gi   = (bf16_t*)(ws + OFF_GI);

    prep_kernel<<<631, 256, 0, stream>>>(len_emb, ipd_emb, fc_w, fc_b,
                                         w_ih, w_hh, lenT, ipdT, wfi, wfh);
    fused_kernel<<<256, 1024, 0, stream>>>(len_x, ipd_x, lenT, ipdT, wfi, wfh,
                                           b_ih, b_hh, gi, out_w, out_b,
                                           (float*)d_out);
}

// Round 10
// 228.353 us; speedup vs baseline: 1.0649x; 1.0184x over previous
//
#include <hip/hip_runtime.h>
#include <hip/hip_bf16.h>

typedef __bf16 bf16_t;
typedef __bf16 bf16x8 __attribute__((ext_vector_type(8)));
typedef float f32x4 __attribute__((ext_vector_type(4)));
typedef unsigned short u16x4 __attribute__((ext_vector_type(4)));

// Operand order: A = weight fragment (gate rows), B = x/h fragment (batch).
// C/D: col(lane&15) = batch, row(quad*4+r) = gate row.
#define MFMA16(a, b, c) __builtin_amdgcn_mfma_f32_16x16x32_bf16((a), (b), (c), 0, 0, 0)

#define BATCH 4096
#define SEQN 128
#define HN 256
#define NLABELS 100
#define TSTEPS 32
#define LEN_VN 1500
#define IPD_VN 256

// Workspace layout (bytes)
#define OFF_LENT   0u           // 1500*64*4 = 384000
#define OFF_IPDT   384000u      // 256*64*4  = 65536
#define OFF_WIH    449536u      // 768*256*2 = 393216
#define OFF_WHH    842752u      // 393216
#define OFF_GI     1235968u     // 4096*32*768*2 = 201326592

__device__ __forceinline__ float sigf(float x) {
    return __builtin_amdgcn_rcpf(1.f + __expf(-x));
}
__device__ __forceinline__ float tanh_fast(float x) {
    return 2.f * __builtin_amdgcn_rcpf(1.f + __expf(-2.f * x)) - 1.f;
}
__device__ __forceinline__ float b2f(unsigned short v) {
    union { unsigned u; float f; } c; c.u = ((unsigned)v) << 16; return c.f;
}
__device__ __forceinline__ f32x4 b2f4(u16x4 v) {
    f32x4 o;
    #pragma unroll
    for (int r = 0; r < 4; ++r) o[r] = b2f(v[r]);
    return o;
}
__device__ __forceinline__ unsigned short f2b(float f) {
    union { bf16_t h; unsigned short s; } c; c.h = (bf16_t)f; return c.s;
}

// LDS-only barrier: does not drain vmcnt; global loads/stores stay in flight.
__device__ __forceinline__ void barrier_lds() {
    asm volatile("s_waitcnt lgkmcnt(0)\n\ts_barrier" ::: "memory");
}
// Per-wave drain of all outstanding global ops (phase boundary).
__device__ __forceinline__ void wait_vm0() {
    asm volatile("s_waitcnt vmcnt(0)" ::: "memory");
}

// ---------------------------------------------------------------------------
// K1: prep, REWRITTEN for coalesced access.
// blocks [0,110): fused embed+FC tables via LDS-staged fc_w (stride-132 pad)
//   and coalesced emb-row staging. Old version read fc_w with 64 distinct
//   cache lines per instruction (stride-512B across lanes) -> ~60 us of TA
//   serialization for 7 MFLOP. Now: all global loads coalesced f32x4; inner
//   product reads LDS (emb row = wave-broadcast; fc_w rows 2-8-way banked).
// blocks [110,302): weight fragments (unchanged logic).
// frag order: wfrag[ct(48)][kt(8)][lane(64)][8], value =
//   W[ct*16 + (lane&15)][kt*32 + (lane>>4)*8 + j]
// ---------------------------------------------------------------------------
#define PREP_TBL_BLOCKS 110
__global__ void prep_kernel(const float* __restrict__ len_emb,
                            const float* __restrict__ ipd_emb,
                            const float* __restrict__ fc_w,
                            const float* __restrict__ fc_b,
                            const float* __restrict__ w_ih,
                            const float* __restrict__ w_hh,
                            float* __restrict__ lenT, float* __restrict__ ipdT,
                            bf16_t* __restrict__ wfrag_ih,
                            bf16_t* __restrict__ wfrag_hh) {
    const int bid = blockIdx.x, tid = threadIdx.x;
    if (bid < PREP_TBL_BLOCKS) {
        __shared__ float w_lds[64 * 132];    // fc_w [e][j], stride 132 (16B-aligned rows)
        __shared__ float emb_lds[16 * 64];   // 16 table rows
        const int row0 = bid * 16;

        // stage fc_w (8192 floats), coalesced f32x4
        #pragma unroll
        for (int k = 0; k < 8; ++k) {
            const int l = k * 1024 + tid * 4;
            const int e = l >> 7, j = l & 127;
            *(f32x4*)(w_lds + e * 132 + j) = *(const f32x4*)(fc_w + l);
        }
        // stage 16 emb rows, coalesced (16 lanes x 16B per row)
        {
            const int r = tid >> 4;
            const int c = (tid & 15) * 4;
            const int grow = row0 + r;
            f32x4 v = {};
            if (grow < LEN_VN)               v = *(const f32x4*)(len_emb + grow * 64 + c);
            else if (grow < LEN_VN + IPD_VN) v = *(const f32x4*)(ipd_emb + (grow - LEN_VN) * 64 + c);
            *(f32x4*)(emb_lds + r * 64 + c) = v;
        }
        __syncthreads();

        const int e = tid & 63;              // output element
        const int r0 = tid >> 6;             // wave id -> rows r0, r0+4, r0+8, r0+12
        const float* wrow_lo = w_lds + e * 132;     // len half [0:64)
        #pragma unroll
        for (int rr = 0; rr < 4; ++rr) {
            const int r = r0 + rr * 4;
            const int grow = row0 + r;
            if (grow >= LEN_VN + IPD_VN) break;      // wave-uniform
            const bool is_len = grow < LEN_VN;       // wave-uniform
            const float* wrow = is_len ? wrow_lo : (wrow_lo + 64);
            f32x4 acc = {};
            #pragma unroll
            for (int c = 0; c < 16; ++c) {
                f32x4 wv = *(const f32x4*)(wrow + c * 4);
                f32x4 ev = *(const f32x4*)(emb_lds + r * 64 + c * 4);   // broadcast
                acc += wv * ev;
            }
            float s = acc[0] + acc[1] + acc[2] + acc[3] + (is_len ? fc_b[e] : 0.f);
            if (is_len) lenT[grow * 64 + e] = s;
            else        ipdT[(grow - LEN_VN) * 64 + e] = s;
        }
    } else {
        const int flat = (bid - PREP_TBL_BLOCKS) * 256 + tid;   // 0..49151
        const int which = flat / 24576;
        const int rem = flat % 24576;
        const int c = rem >> 9;
        const int kt = (rem >> 6) & 7;
        const int lane = rem & 63;
        const int g = c * 16 + (lane & 15);
        const int k0 = kt * 32 + (lane >> 4) * 8;
        const float* src = (which == 0 ? w_ih : w_hh) + g * 256 + k0;
        bf16_t* dst = (which == 0 ? wfrag_ih : wfrag_hh) + ((c * 8 + kt) * 64 + lane) * 8;
        f32x4 s0 = *(const f32x4*)(src);
        f32x4 s1 = *(const f32x4*)(src + 4);
        bf16x8 o;
        #pragma unroll
        for (int j = 0; j < 4; ++j) { o[j] = (bf16_t)s0[j]; o[4 + j] = (bf16_t)s1[j]; }
        *(bf16x8*)dst = o;
    }
}

// ---------------------------------------------------------------------------
// K2: FUSED input-GEMM + GRU (UNCHANGED from round 9 — frozen for
// attribution). 256 blocks x 1024 threads (16 waves, 4/SIMD).
// ---------------------------------------------------------------------------
__global__ void __launch_bounds__(1024, 4)
fused_kernel(const int* __restrict__ len_x, const int* __restrict__ ipd_x,
             const float* __restrict__ lenT, const float* __restrict__ ipdT,
             const bf16_t* __restrict__ wfrag_ih,
             const bf16_t* __restrict__ wfrag_hh,
             const float* __restrict__ b_ih, const float* __restrict__ b_hh,
             bf16_t* gi,
             const float* __restrict__ out_w,
             const float* __restrict__ out_b,
             float* __restrict__ out) {
    __shared__ char smem[147456];
    bf16_t* wlds = (bf16_t*)smem;               // 128 KB: per-wave n-tile
    bf16_t* dbuf = (bf16_t*)(smem + 131072);    // 16 KB: x-stage / h double buf
    float* h_fin = (float*)smem;                // aliases wlds (post-loop)

    const int tid = threadIdx.x;
    const int lane = tid & 63;
    const int w = tid >> 6;          // wave 0..15
    const int bt = blockIdx.x;
    const int quad = lane >> 4;
    const int b = lane & 15;

    bf16_t* gib = gi + (size_t)bt * 48 * 32 * 256 + lane * 4;
    const bf16_t* wb = &wlds[w * 8 * 512 + lane * 8];

    // ===================== PHASE 1: input-side GEMM ========================
    {
        bf16x8 wri[2][8];
        #pragma unroll
        for (int cc = 0; cc < 2; ++cc) {
            const int ct = cc * 16 + w;
            #pragma unroll
            for (int kt = 0; kt < 8; ++kt)
                wri[cc][kt] = *(const bf16x8*)(wfrag_ih + ((ct * 8 + kt) * 64 + lane) * 8);
        }
        #pragma unroll
        for (int kt = 0; kt < 8; ++kt)
            *(bf16x8*)&wlds[(w * 8 + kt) * 512 + lane * 8] =
                *(const bf16x8*)(wfrag_ih + (((32 + w) * 8 + kt) * 64 + lane) * 8);

        f32x4 bias0 = *(const f32x4*)(b_ih + w * 16 + quad * 4)
                    + *(const f32x4*)(b_hh + w * 16 + quad * 4);
        f32x4 bias1 = *(const f32x4*)(b_ih + 256 + w * 16 + quad * 4)
                    + *(const f32x4*)(b_hh + 256 + w * 16 + quad * 4);
        f32x4 bias2 = *(const f32x4*)(b_ih + 512 + w * 16 + quad * 4);

        const int sub = tid & 511;
        const int pr = sub >> 3;
        const int sub8 = sub & 7;
        const int grow = pr & 15;
        const int p = pr >> 4;
        const int e0 = sub8 * 8;
        const int b_row = bt * 16 + grow;
        const int goff = (2 * p + (sub8 >> 2)) * 512 + ((sub8 & 3) * 16 + grow) * 8;

        auto do_gather = [&](int t) {
            const int seq = t * 4 + p;
            const int v1 = len_x[b_row * SEQN + seq];
            const int v2 = ipd_x[b_row * SEQN + seq];
            const float* lp = lenT + v1 * 64 + e0;
            const float* ip = ipdT + v2 * 64 + e0;
            f32x4 a0 = *(const f32x4*)lp + *(const f32x4*)ip;
            f32x4 a1 = *(const f32x4*)(lp + 4) + *(const f32x4*)(ip + 4);
            bf16x8 o;
            #pragma unroll
            for (int j = 0; j < 4; ++j) { o[j] = (bf16_t)a0[j]; o[4 + j] = (bf16_t)a1[j]; }
            *(bf16x8*)&dbuf[(t & 1) * 4096 + goff] = o;
        };

        if (tid < 512) do_gather(0);

        for (int t = 0; t < TSTEPS; ++t) {
            barrier_lds();
            if (t + 1 < TSTEPS && tid < 512) do_gather(t + 1);

            f32x4 acc0 = bias0, acc1 = bias1, acc2 = bias2;
            const bf16_t* ab = &dbuf[(t & 1) * 4096 + lane * 8];
            #pragma unroll
            for (int kt = 0; kt < 8; ++kt) {
                bf16x8 xf = *(const bf16x8*)(ab + kt * 512);
                bf16x8 w5 = *(const bf16x8*)(wb + kt * 512);
                acc0 = MFMA16(wri[0][kt], xf, acc0);
                acc1 = MFMA16(wri[1][kt], xf, acc1);
                acc2 = MFMA16(w5, xf, acc2);
            }

            u16x4 o0, o1, o2;
            #pragma unroll
            for (int r = 0; r < 4; ++r) {
                o0[r] = f2b(acc0[r]); o1[r] = f2b(acc1[r]); o2[r] = f2b(acc2[r]);
            }
            *(u16x4*)(gib + ((size_t)(w) * 32 + t) * 256) = o0;
            *(u16x4*)(gib + ((size_t)(16 + w) * 32 + t) * 256) = o1;
            *(u16x4*)(gib + ((size_t)(32 + w) * 32 + t) * 256) = o2;
        }
    }

    // ===================== PHASE boundary ==================================
    barrier_lds();
    wait_vm0();

    // ===================== PHASE 2: recurrent GRU ==========================
    bf16_t* h_lds = dbuf;

    bf16x8 wr[2][8];
    #pragma unroll
    for (int cc = 0; cc < 2; ++cc) {
        const int ct = cc * 16 + w;
        #pragma unroll
        for (int kt = 0; kt < 8; ++kt)
            wr[cc][kt] = *(const bf16x8*)(wfrag_hh + ((ct * 8 + kt) * 64 + lane) * 8);
    }
    #pragma unroll
    for (int kt = 0; kt < 8; ++kt)
        *(bf16x8*)&wlds[(w * 8 + kt) * 512 + lane * 8] =
            *(const bf16x8*)(wfrag_hh + (((32 + w) * 8 + kt) * 64 + lane) * 8);

    const f32x4 bhn = *(const f32x4*)(b_hh + (32 + w) * 16 + quad * 4);

    for (int i = tid; i < 4096; i += 1024) h_lds[4096 + i] = (bf16_t)0.f;

    const int j0 = 16 * w + 4 * quad;
    const int woff = (j0 >> 5) * 512 + ((((j0 >> 3) & 3)) * 16 + b) * 8 + (j0 & 7);

    u16x4 gc0 = *(const u16x4*)(gib + ((size_t)(w) * 32) * 256);
    u16x4 gc1 = *(const u16x4*)(gib + ((size_t)(16 + w) * 32) * 256);
    u16x4 gc2 = *(const u16x4*)(gib + ((size_t)(32 + w) * 32) * 256);

    f32x4 hprev = {};

    for (int t = 0; t < TSTEPS; ++t) {
        barrier_lds();

        f32x4 acc0 = b2f4(gc0);
        f32x4 acc1 = b2f4(gc1);
        f32x4 acc2 = bhn;
        u16x4 g2cur = gc2;

        if (t + 1 < TSTEPS) {
            gc0 = *(const u16x4*)(gib + ((size_t)(w) * 32 + t + 1) * 256);
            gc1 = *(const u16x4*)(gib + ((size_t)(16 + w) * 32 + t + 1) * 256);
            gc2 = *(const u16x4*)(gib + ((size_t)(32 + w) * 32 + t + 1) * 256);
        }

        const bf16_t* hb = &h_lds[((t + 1) & 1) * 4096 + lane * 8];
        #pragma unroll
        for (int kt = 0; kt < 8; ++kt) {
            bf16x8 hf = *(const bf16x8*)(hb + kt * 512);
            bf16x8 w5 = *(const bf16x8*)(wb + kt * 512);
            acc0 = MFMA16(wr[0][kt], hf, acc0);
            acc1 = MFMA16(wr[1][kt], hf, acc1);
            acc2 = MFMA16(w5, hf, acc2);
        }

        f32x4 rg, zg;
        #pragma unroll
        for (int r = 0; r < 4; ++r) { rg[r] = sigf(acc0[r]); zg[r] = sigf(acc1[r]); }
        f32x4 u = b2f4(g2cur) + rg * acc2;
        f32x4 ng;
        #pragma unroll
        for (int r = 0; r < 4; ++r) ng[r] = tanh_fast(u[r]);
        f32x4 hn = ng + zg * (hprev - ng);
        hprev = hn;

        u16x4 o;
        #pragma unroll
        for (int r = 0; r < 4; ++r) o[r] = f2b(hn[r]);
        *(u16x4*)(&h_lds[(t & 1) * 4096 + woff]) = o;
    }

    __syncthreads();

    *(f32x4*)(h_fin + b * 260 + j0) = hprev;
    __syncthreads();

    for (int i = tid; i < 16 * NLABELS; i += 1024) {
        const int row = i / NLABELS;
        const int cl = i - row * NLABELS;
        const f32x4* wrow = (const f32x4*)(out_w + cl * 256);
        const f32x4* hr = (const f32x4*)(h_fin + row * 260);
        f32x4 acc = {0.f, 0.f, 0.f, 0.f};
        #pragma unroll 4
        for (int k = 0; k < 64; ++k) acc += hr[k] * wrow[k];
        out[(bt * 16 + row) * NLABELS + cl] =
            out_b[cl] + acc[0] + acc[1] + acc[2] + acc[3];
    }
}

// ---------------------------------------------------------------------------
extern "C" void kernel_launch(void* const* d_in, const int* in_sizes, int n_in,
                              void* d_out, int out_size, void* d_ws, size_t ws_size,
                              hipStream_t stream) {
    (void)in_sizes; (void)n_in; (void)out_size; (void)ws_size;
    const int*   len_x   = (const int*)d_in[0];
    const int*   ipd_x   = (const int*)d_in[1];
    const float* len_emb = (const float*)d_in[2];
    const float* ipd_emb = (const float*)d_in[3];
    const float* fc_w    = (const float*)d_in[4];
    const float* fc_b    = (const float*)d_in[5];
    const float* w_ih    = (const float*)d_in[6];
    const float* w_hh    = (const float*)d_in[7];
    const float* b_ih    = (const float*)d_in[8];
    const float* b_hh    = (const float*)d_in[9];
    const float* out_w   = (const float*)d_in[10];
    const float* out_b   = (const float*)d_in[11];

    char* ws = (char*)d_ws;
    float*  lenT = (float*)(ws + OFF_LENT);
    float*  ipdT = (float*)(ws + OFF_IPDT);
    bf16_t* wfi  = (bf16_t*)(ws + OFF_WIH);
    bf16_t* wfh  = (bf16_t*)(ws + OFF_WHH);
    bf16_t* gi   = (bf16_t*)(ws + OFF_GI);

    prep_kernel<<<302, 256, 0, stream>>>(len_emb, ipd_emb, fc_w, fc_b,
                                         w_ih, w_hh, lenT, ipdT, wfi, wfh);
    fused_kernel<<<256, 1024, 0, stream>>>(len_x, ipd_x, lenT, ipdT, wfi, wfh,
                                           b_ih, b_hh, gi, out_w, out_b,
                                           (float*)d_out);
}